// Round 2
// 316.476 us; speedup vs baseline: 1.0405x; 1.0405x over previous
//
#include <hip/hip_runtime.h>

// Haar (db1) 2-D DWT, non-overlapping 2x2 block transform.
// Input:  (16, 3, 1024, 1024) fp32
// Output: 4 planes (cA, cH, cV, cD), each (16, 3, 512, 512) fp32, concat flat.
//
// Memory-bound streaming kernel: 192 MiB read + 192 MiB write, every byte
// touched exactly once. This version:
//  - 2 output cols per thread: ONE lane-contiguous 16B load per input row
//    (100% per-instruction coalescing; the 329us version had stride-32B
//    lanes -> 50% per-instruction utilization, 2x transactions)
//  - 8B stores per plane (512 B per wave-store, fully coalesced)
//  - non-temporal loads AND stores: pure streaming, avoid L2 write-allocate
//    pollution competing with the read stream.
// NOTE: __builtin_nontemporal_* requires native vector types, not the
// HIP_vector_type classes (float4/float2) — use ext_vector_type.

#define IN_W   1024
#define IN_H   1024
#define IMG_IN (IN_H * IN_W)
#define OUT_W  512
#define OUT_H  512
#define IMG_OUT (OUT_H * OUT_W)
#define N_IMG  48                        // B*C = 16*3
#define PLANE  ((size_t)N_IMG * IMG_OUT) // elements per output plane

typedef float f32x4 __attribute__((ext_vector_type(4)));
typedef float f32x2 __attribute__((ext_vector_type(2)));

__global__ __launch_bounds__(256) void haar_dwt2_kernel(
    const float* __restrict__ x, float* __restrict__ out)
{
    int t = blockIdx.x * blockDim.x + threadIdx.x;

    int ox   = t & 255;        // 16B group within input row: 256 per row
    int rest = t >> 8;
    int oy   = rest & 511;     // output row
    int img  = rest >> 9;      // (b,c) image index, 0..47

    const float* img_base = x + (size_t)img * IMG_IN;
    const f32x4* row0 = (const f32x4*)(img_base + (size_t)(2 * oy)     * IN_W);
    const f32x4* row1 = (const f32x4*)(img_base + (size_t)(2 * oy + 1) * IN_W);

    // Lane-contiguous: lane i loads 16B at index (base + i). 16B/lane.
    f32x4 a = __builtin_nontemporal_load(row0 + ox);  // even row, cols [4ox .. 4ox+3]
    f32x4 b = __builtin_nontemporal_load(row1 + ox);  // odd  row, cols [4ox .. 4ox+3]

    // Input col pairs (4ox,4ox+1) -> output col 2ox ; (4ox+2,4ox+3) -> 2ox+1.
    // Keep arithmetic order identical to reference (absmax == 0.0).
    f32x2 cA, cH, cV, cD;

    cA.x = (a.x + a.y + b.x + b.y) * 0.5f;
    cH.x = (a.x + a.y - b.x - b.y) * 0.5f;
    cV.x = (a.x - a.y + b.x - b.y) * 0.5f;
    cD.x = (a.x - a.y - b.x + b.y) * 0.5f;

    cA.y = (a.z + a.w + b.z + b.w) * 0.5f;
    cH.y = (a.z + a.w - b.z - b.w) * 0.5f;
    cV.y = (a.z - a.w + b.z - b.w) * 0.5f;
    cD.y = (a.z - a.w - b.z + b.w) * 0.5f;

    size_t o = (size_t)img * IMG_OUT + (size_t)oy * OUT_W + (size_t)(2 * ox);
    __builtin_nontemporal_store(cA, (f32x2*)(out + 0 * PLANE + o));
    __builtin_nontemporal_store(cH, (f32x2*)(out + 1 * PLANE + o));
    __builtin_nontemporal_store(cV, (f32x2*)(out + 2 * PLANE + o));
    __builtin_nontemporal_store(cD, (f32x2*)(out + 3 * PLANE + o));
}

extern "C" void kernel_launch(void* const* d_in, const int* in_sizes, int n_in,
                              void* d_out, int out_size, void* d_ws, size_t ws_size,
                              hipStream_t stream)
{
    const float* x = (const float*)d_in[0];
    float* out = (float*)d_out;

    // 48 images * 512 output rows * 256 col-groups = 6,291,456 threads
    int total_threads = N_IMG * OUT_H * 256;
    int block = 256;
    int grid = total_threads / block;  // 24576

    haar_dwt2_kernel<<<grid, block, 0, stream>>>(x, out);
}